// Round 3
// baseline (285.388 us; speedup 1.0000x reference)
//
#include <hip/hip_runtime.h>
#include <math.h>

#define BATCH 8
#define NNODE 2048
#define DIN   1024
#define DM    256
#define ROWS_TOTAL (BATCH * NNODE)   // 16384

#define LOG2E 1.4426950408889634f
#define Q127  0.011359803471566641f   // LOG2E / 127

typedef unsigned short u16;
typedef __attribute__((ext_vector_type(8))) short short8;   // 8 bf16
typedef __attribute__((ext_vector_type(4))) float f32x4;

__device__ __forceinline__ u16 f2b(float f) {   // fp32 -> bf16 RNE
    union { float f; unsigned u; } v; v.f = f;
    unsigned r = v.u + 0x7fffu + ((v.u >> 16) & 1u);
    return (u16)(r >> 16);
}
__device__ __forceinline__ float b2f(u16 h) {
    union { unsigned u; float f; } v; v.u = ((unsigned)h) << 16; return v.f;
}
// signed byte k (0..3) of dword -> float
__device__ __forceinline__ float dqi(unsigned wd, int k) {
    return (float)((int)(wd << ((3 - k) * 8)) >> 24);
}

// ---------------------------------------------------------------------------
// Kernel 0: Wt[c][k] = bf16(W[k][c])
// ---------------------------------------------------------------------------
__global__ __launch_bounds__(256) void cvgm_prep_w(
    const float* __restrict__ W, u16* __restrict__ Wt)
{
    __shared__ float t[32][33];
    const int tx = threadIdx.x & 31, ty = threadIdx.x >> 5;
    const int k0 = blockIdx.x * 32, c0 = blockIdx.y * 32;
    #pragma unroll
    for (int r = 0; r < 4; ++r) {
        const int kl = ty * 4 + r;
        t[kl][tx] = W[(size_t)(k0 + kl) * DM + c0 + tx];
    }
    __syncthreads();
    #pragma unroll
    for (int r = 0; r < 4; ++r) {
        const int cl = ty * 4 + r;
        Wt[(size_t)(c0 + cl) * DIN + k0 + tx] = f2b(t[tx][cl]);
    }
}

// ---------------------------------------------------------------------------
// Kernel 1: P = bf16(l2norm(X@W + b)).  64 rows x 256 cols per block,
// 512 threads = 8 waves (2 row-halves x 4 col-quarters), BK=64.
// grid (256, 2): y selects drone/sat.
// ---------------------------------------------------------------------------
__global__ __launch_bounds__(512) void cvgm_proj_mfma(
    const float* __restrict__ Xd, const float* __restrict__ Xs,
    const u16* __restrict__ Wt, const float* __restrict__ bias,
    u16* __restrict__ Pd, u16* __restrict__ Ps)
{
    __shared__ u16 As[64 * 64];     // 8 KB  chunk-swizzled [row][k]
    __shared__ u16 Bs[256 * 64];    // 32 KB chunk-swizzled [col][k]
    __shared__ float rsum[4][64];

    const float* X = blockIdx.y ? Xs : Xd;
    u16* P = blockIdx.y ? Ps : Pd;

    const int tid = threadIdx.x;
    const int lane = tid & 63, wid = tid >> 6;
    const int wr = wid >> 2, wc = wid & 3;
    const int l15 = lane & 15, l4 = lane >> 4;
    const int row0 = blockIdx.x * 64;

    f32x4 acc[2][4];
    #pragma unroll
    for (int m = 0; m < 2; ++m)
        #pragma unroll
        for (int n = 0; n < 4; ++n) acc[m][n] = (f32x4){0.f, 0.f, 0.f, 0.f};

    const int arow = tid >> 3, ac = tid & 7;   // A: 1 short8 chunk / thread

    for (int k0 = 0; k0 < DIN; k0 += 64) {
        const float* src = X + (size_t)(row0 + arow) * DIN + k0 + ac * 8;
        const float4 x0 = *(const float4*)src;
        const float4 x1 = *(const float4*)(src + 4);
        short8 wb[4];
        #pragma unroll
        for (int it = 0; it < 4; ++it) {
            const int id = it * 512 + tid;
            const int col = id >> 3, cc = id & 7;
            wb[it] = *(const short8*)(Wt + (size_t)col * DIN + k0 + cc * 8);
        }
        __syncthreads();
        short8 ap;
        ap[0]=(short)f2b(x0.x); ap[1]=(short)f2b(x0.y); ap[2]=(short)f2b(x0.z); ap[3]=(short)f2b(x0.w);
        ap[4]=(short)f2b(x1.x); ap[5]=(short)f2b(x1.y); ap[6]=(short)f2b(x1.z); ap[7]=(short)f2b(x1.w);
        *(short8*)(As + (arow * 8 + (ac ^ (arow & 7))) * 8) = ap;
        #pragma unroll
        for (int it = 0; it < 4; ++it) {
            const int id = it * 512 + tid;
            const int col = id >> 3, cc = id & 7;
            *(short8*)(Bs + (col * 8 + (cc ^ (col & 7))) * 8) = wb[it];
        }
        __syncthreads();
        #pragma unroll
        for (int ks = 0; ks < 2; ++ks) {
            const int ch = ks * 4 + l4;
            short8 af[2], bfr[4];
            #pragma unroll
            for (int m = 0; m < 2; ++m) {
                const int row = wr * 32 + m * 16 + l15;
                af[m] = *(const short8*)(As + (row * 8 + (ch ^ (row & 7))) * 8);
            }
            #pragma unroll
            for (int n = 0; n < 4; ++n) {
                const int col = wc * 64 + n * 16 + l15;
                bfr[n] = *(const short8*)(Bs + (col * 8 + (ch ^ (col & 7))) * 8);
            }
            #pragma unroll
            for (int m = 0; m < 2; ++m)
                #pragma unroll
                for (int n = 0; n < 4; ++n)
                    acc[m][n] = __builtin_amdgcn_mfma_f32_16x16x32_bf16(af[m], bfr[n], acc[m][n], 0, 0, 0);
        }
        __syncthreads();
    }

    #pragma unroll
    for (int n = 0; n < 4; ++n) {
        const float bv = bias[wc * 64 + n * 16 + l15];
        #pragma unroll
        for (int m = 0; m < 2; ++m)
            #pragma unroll
            for (int r = 0; r < 4; ++r) acc[m][n][r] += bv;
    }
    #pragma unroll
    for (int m = 0; m < 2; ++m)
        #pragma unroll
        for (int r = 0; r < 4; ++r) {
            float s = 0.f;
            #pragma unroll
            for (int n = 0; n < 4; ++n) s += acc[m][n][r] * acc[m][n][r];
            s += __shfl_xor(s, 1); s += __shfl_xor(s, 2);
            s += __shfl_xor(s, 4); s += __shfl_xor(s, 8);
            if (l15 == 0) rsum[wc][wr * 32 + m * 16 + l4 * 4 + r] = s;
        }
    __syncthreads();
    #pragma unroll
    for (int m = 0; m < 2; ++m)
        #pragma unroll
        for (int r = 0; r < 4; ++r) {
            const int row = wr * 32 + m * 16 + l4 * 4 + r;
            const float tot = rsum[0][row] + rsum[1][row] + rsum[2][row] + rsum[3][row];
            const float inv = 1.0f / fmaxf(sqrtf(tot), 1e-12f);
            #pragma unroll
            for (int n = 0; n < 4; ++n) {
                const int col = wc * 64 + n * 16 + l15;
                P[(size_t)(row0 + row) * DM + col] = f2b(acc[m][n][r] * inv);
            }
        }
}

// ---------------------------------------------------------------------------
// Kernel 2: M0[b] = D[b]@S[b]^T  bf16 MFMA 128x128 tile; writes bf16 M0 and
// (WQ) int8-quantized M0q = rint(M0*127).
// ---------------------------------------------------------------------------
template <int WQ>
__global__ __launch_bounds__(256) void cvgm_m0_mfma(
    const u16* __restrict__ Dp, const u16* __restrict__ Sp,
    u16* __restrict__ C, char* __restrict__ Cq)
{
    __shared__ u16 As[128 * 64];
    __shared__ u16 Bs[128 * 64];

    const int tid = threadIdx.x;
    const int lane = tid & 63, wid = tid >> 6;
    const int wr = wid >> 1, wc = wid & 1;
    const int l15 = lane & 15, l4 = lane >> 4;
    const int bb = blockIdx.z;
    const int i0 = blockIdx.y * 128, j0 = blockIdx.x * 128;
    const u16* Db = Dp + (size_t)bb * NNODE * DM;
    const u16* Sb = Sp + (size_t)bb * NNODE * DM;

    f32x4 acc[4][4];
    #pragma unroll
    for (int m = 0; m < 4; ++m)
        #pragma unroll
        for (int n = 0; n < 4; ++n) acc[m][n] = (f32x4){0.f, 0.f, 0.f, 0.f};

    for (int k0 = 0; k0 < DM; k0 += 64) {
        short8 ra[4], rb[4];
        #pragma unroll
        for (int it = 0; it < 4; ++it) {
            const int id = it * 256 + tid;
            const int row = id >> 3, c = id & 7;
            ra[it] = *(const short8*)(Db + (size_t)(i0 + row) * DM + k0 + c * 8);
            rb[it] = *(const short8*)(Sb + (size_t)(j0 + row) * DM + k0 + c * 8);
        }
        __syncthreads();
        #pragma unroll
        for (int it = 0; it < 4; ++it) {
            const int id = it * 256 + tid;
            const int row = id >> 3, c = id & 7;
            const int sl = row * 8 + (c ^ (row & 7));
            *(short8*)(As + sl * 8) = ra[it];
            *(short8*)(Bs + sl * 8) = rb[it];
        }
        __syncthreads();
        #pragma unroll
        for (int ks = 0; ks < 2; ++ks) {
            const int ch = ks * 4 + l4;
            short8 af[4], bfr[4];
            #pragma unroll
            for (int m = 0; m < 4; ++m) {
                const int row = wr * 64 + m * 16 + l15;
                af[m] = *(const short8*)(As + (row * 8 + (ch ^ (row & 7))) * 8);
            }
            #pragma unroll
            for (int n = 0; n < 4; ++n) {
                const int col = wc * 64 + n * 16 + l15;
                bfr[n] = *(const short8*)(Bs + (col * 8 + (ch ^ (col & 7))) * 8);
            }
            #pragma unroll
            for (int m = 0; m < 4; ++m)
                #pragma unroll
                for (int n = 0; n < 4; ++n)
                    acc[m][n] = __builtin_amdgcn_mfma_f32_16x16x32_bf16(af[m], bfr[n], acc[m][n], 0, 0, 0);
        }
        __syncthreads();
    }

    u16* Cb = C + (size_t)bb * NNODE * NNODE;
    char* Cqb = Cq + (size_t)bb * NNODE * NNODE;
    #pragma unroll
    for (int m = 0; m < 4; ++m) {
        const int row = i0 + wr * 64 + m * 16 + l4 * 4;
        #pragma unroll
        for (int n = 0; n < 4; ++n) {
            const int col = j0 + wc * 64 + n * 16 + l15;
            #pragma unroll
            for (int r = 0; r < 4; ++r) {
                const float val = acc[m][n][r];
                Cb[(size_t)(row + r) * NNODE + col] = f2b(val);
                if constexpr (WQ) {
                    int q = __float2int_rn(val * 127.f);
                    q = q > 127 ? 127 : (q < -127 ? -127 : q);
                    Cqb[(size_t)(row + r) * NNODE + col] = (char)q;
                }
            }
        }
    }
}

// ---------------------------------------------------------------------------
// Kernel 3: fused Sinkhorn iteration (row phase + col-partial phase).
// Block owns a RPC-row stripe: reads it from global ONCE (stash in LDS).
// Phase A: u2[i] = log2 sum_j exp2(x*scale - v2[j])  (one wave per row group)
// Phase B: ps[chunk][j] = sum_i exp2(x*scale - u2[i]) over stripe rows.
// ISQ=1: int8 storage (RPC=32); ISQ=0: bf16 storage (RPC=16).
// ---------------------------------------------------------------------------
template <int ISQ>
__global__ __launch_bounds__(256) void cvgm_rc(
    const void* __restrict__ Mq_, const float* __restrict__ v2,
    float* __restrict__ u2, float* __restrict__ ps)
{
    constexpr int RPC = ISQ ? 32 : 16;
    constexpr int NCH = NNODE / RPC;
    constexpr int RB  = ISQ ? NNODE : NNODE * 2;   // row bytes
    __shared__ alignas(16) char stripe[RPC * RB];  // 64 KB both tiers
    __shared__ float u2s[RPC];

    const int tid = threadIdx.x;
    const int lane = tid & 63, w = tid >> 6;
    const int b = blockIdx.y, chunk = blockIdx.x;
    const size_t grow0 = ((size_t)b << 11) + chunk * RPC;

    // prefetch v2 (32 cols per lane: col = seg*1024 + lane*16 + k)
    float vl[32];
    const float* v2b = v2 + (b << 11);
    #pragma unroll
    for (int s = 0; s < 2; ++s)
        #pragma unroll
        for (int k = 0; k < 4; ++k)
            *(float4*)(vl + s * 16 + k * 4) =
                *(const float4*)(v2b + s * 1024 + lane * 16 + k * 4);

    const char* gbase = (const char*)Mq_ + grow0 * RB;
    constexpr int RW = RPC / 4;   // rows per wave
    #pragma unroll
    for (int rr = 0; rr < RW; ++rr) {
        const int r = w * RW + rr;
        float s = 0.f;
        if constexpr (ISQ) {
            const char* rsrc = gbase + (size_t)r * RB;
            #pragma unroll
            for (int seg = 0; seg < 2; ++seg) {
                const int4 d = *(const int4*)(rsrc + seg * 1024 + lane * 16);
                *(int4*)(stripe + r * RB + seg * 1024 + lane * 16) = d;
                const unsigned uu[4] = {(unsigned)d.x, (unsigned)d.y, (unsigned)d.z, (unsigned)d.w};
                #pragma unroll
                for (int q = 0; q < 4; ++q)
                    #pragma unroll
                    for (int k = 0; k < 4; ++k)
                        s += exp2f(fmaf(dqi(uu[q], k), Q127, -vl[seg * 16 + q * 4 + k]));
            }
        } else {
            const char* rsrc = gbase + (size_t)r * RB;
            #pragma unroll
            for (int seg = 0; seg < 2; ++seg) {
                const int4 d0 = *(const int4*)(rsrc + seg * 2048 + lane * 32);
                const int4 d1 = *(const int4*)(rsrc + seg * 2048 + lane * 32 + 16);
                *(int4*)(stripe + r * RB + seg * 2048 + lane * 32) = d0;
                *(int4*)(stripe + r * RB + seg * 2048 + lane * 32 + 16) = d1;
                const unsigned uu[8] = {(unsigned)d0.x, (unsigned)d0.y, (unsigned)d0.z, (unsigned)d0.w,
                                        (unsigned)d1.x, (unsigned)d1.y, (unsigned)d1.z, (unsigned)d1.w};
                #pragma unroll
                for (int q = 0; q < 8; ++q) {
                    union { unsigned u; float f; } lo, hi;
                    lo.u = uu[q] << 16; hi.u = uu[q] & 0xffff0000u;
                    s += exp2f(fmaf(lo.f, LOG2E, -vl[seg * 16 + q * 2 + 0]));
                    s += exp2f(fmaf(hi.f, LOG2E, -vl[seg * 16 + q * 2 + 1]));
                }
            }
        }
        #pragma unroll
        for (int off = 1; off < 64; off <<= 1) s += __shfl_xor(s, off);
        if (lane == 0) {
            const float l2 = __log2f(s);
            u2[grow0 + r] = l2;
            u2s[r] = l2;
        }
    }
    __syncthreads();

    // Phase B: thread owns 8 adjacent cols
    const int j = tid * 8;
    float sc[8] = {0.f, 0.f, 0.f, 0.f, 0.f, 0.f, 0.f, 0.f};
    #pragma unroll 4
    for (int i = 0; i < RPC; ++i) {
        const float ui = u2s[i];
        if constexpr (ISQ) {
            const unsigned* pw = (const unsigned*)(stripe + i * RB + j);
            const unsigned w0 = pw[0], w1 = pw[1];
            #pragma unroll
            for (int k = 0; k < 4; ++k) {
                sc[k]     += exp2f(fmaf(dqi(w0, k), Q127, -ui));
                sc[4 + k] += exp2f(fmaf(dqi(w1, k), Q127, -ui));
            }
        } else {
            const unsigned* pw = (const unsigned*)(stripe + i * RB + j * 2);
            #pragma unroll
            for (int q = 0; q < 4; ++q) {
                union { unsigned u; float f; } lo, hi;
                lo.u = pw[q] << 16; hi.u = pw[q] & 0xffff0000u;
                sc[q * 2 + 0] += exp2f(fmaf(lo.f, LOG2E, -ui));
                sc[q * 2 + 1] += exp2f(fmaf(hi.f, LOG2E, -ui));
            }
        }
    }
    float* dst = ps + ((size_t)(b * NCH + chunk)) * NNODE + j;
    *(float4*)(dst)     = make_float4(sc[0], sc[1], sc[2], sc[3]);
    *(float4*)(dst + 4) = make_float4(sc[4], sc[5], sc[6], sc[7]);
}

// ---------------------------------------------------------------------------
// Kernel 4: v2[b,j] = log2( sum over nch chunk partials )
// ---------------------------------------------------------------------------
__global__ __launch_bounds__(256) void cvgm_merge(
    const float* __restrict__ ps, float* __restrict__ v2, int nch)
{
    const int idx = blockIdx.x * 256 + threadIdx.x;
    const int b = idx >> 11, j = idx & 2047;
    float s = 0.f;
    #pragma unroll 8
    for (int c = 0; c < nch; ++c) s += ps[(size_t)(b * nch + c) * NNODE + j];
    v2[idx] = __log2f(s);
}

// ---------------------------------------------------------------------------
// Kernel 5: assignment = exp2(M0*log2e - u2 - v2) -> out fp32; spart[row].
// grid (64, 8): 32-row stripes, one wave per 8 rows.
// ---------------------------------------------------------------------------
__global__ __launch_bounds__(256) void cvgm_final(
    const u16* __restrict__ M0b, const float* __restrict__ u2,
    const float* __restrict__ v2, float* __restrict__ out,
    float* __restrict__ spart)
{
    const int tid = threadIdx.x;
    const int lane = tid & 63, w = tid >> 6;
    const int b = blockIdx.y, chunk = blockIdx.x;
    const size_t grow0 = ((size_t)b << 11) + chunk * 32;

    float vl[32];
    const float* v2b = v2 + (b << 11);
    #pragma unroll
    for (int s = 0; s < 2; ++s)
        #pragma unroll
        for (int k = 0; k < 4; ++k)
            *(float4*)(vl + s * 16 + k * 4) =
                *(const float4*)(v2b + s * 1024 + lane * 16 + k * 4);

    #pragma unroll
    for (int rr = 0; rr < 8; ++rr) {
        const size_t grow = grow0 + w * 8 + rr;
        const float ui = u2[grow];
        const char* rsrc = (const char*)(M0b + grow * NNODE);
        float* drow = out + grow * NNODE;
        float acc = 0.f;
        #pragma unroll
        for (int seg = 0; seg < 2; ++seg) {
            const int4 d0 = *(const int4*)(rsrc + seg * 2048 + lane * 32);
            const int4 d1 = *(const int4*)(rsrc + seg * 2048 + lane * 32 + 16);
            const unsigned uu[8] = {(unsigned)d0.x, (unsigned)d0.y, (unsigned)d0.z, (unsigned)d0.w,
                                    (unsigned)d1.x, (unsigned)d1.y, (unsigned)d1.z, (unsigned)d1.w};
            float a[16];
            #pragma unroll
            for (int q = 0; q < 8; ++q) {
                union { unsigned u; float f; } lo, hi;
                lo.u = uu[q] << 16; hi.u = uu[q] & 0xffff0000u;
                const float e0 = exp2f(fmaf(lo.f, LOG2E, -(ui + vl[seg * 16 + q * 2 + 0])));
                const float e1 = exp2f(fmaf(hi.f, LOG2E, -(ui + vl[seg * 16 + q * 2 + 1])));
                a[q * 2 + 0] = e0; a[q * 2 + 1] = e1;
                acc += e0 * lo.f + e1 * hi.f;
            }
            float* dseg = drow + seg * 1024 + lane * 16;
            #pragma unroll
            for (int k = 0; k < 4; ++k)
                *(float4*)(dseg + k * 4) = make_float4(a[k*4+0], a[k*4+1], a[k*4+2], a[k*4+3]);
        }
        #pragma unroll
        for (int off = 1; off < 64; off <<= 1) acc += __shfl_xor(acc, off);
        if (lane == 0) spart[grow] = acc;
    }
}

// ---------------------------------------------------------------------------
// Kernel 6: match_score[b] = sum(spart[b,:]) / 2048
// ---------------------------------------------------------------------------
__global__ __launch_bounds__(256) void cvgm_score(
    const float* __restrict__ spart, float* __restrict__ score)
{
    const int b = blockIdx.x;
    float acc = 0.f;
    for (int t = threadIdx.x; t < NNODE; t += 256) acc += spart[(b << 11) + t];
    #pragma unroll
    for (int off = 1; off < 64; off <<= 1) acc += __shfl_xor(acc, off);
    __shared__ float sh[4];
    if ((threadIdx.x & 63) == 0) sh[threadIdx.x >> 6] = acc;
    __syncthreads();
    if (threadIdx.x == 0) score[b] = (sh[0] + sh[1] + sh[2] + sh[3]) * (1.0f / 2048.0f);
}

// ---------------------------------------------------------------------------
extern "C" void kernel_launch(void* const* d_in, const int* in_sizes, int n_in,
                              void* d_out, int out_size, void* d_ws, size_t ws_size,
                              hipStream_t stream) {
    (void)in_sizes; (void)n_in; (void)out_size;
    const float* drone = (const float*)d_in[0];
    const float* sat   = (const float*)d_in[1];
    const float* W     = (const float*)d_in[2];
    const float* bias  = (const float*)d_in[3];

    float* out   = (float*)d_out;
    float* score = out + (size_t)BATCH * NNODE * NNODE;

    char* ws = (char*)d_ws;
    const size_t SZ_M0B  = (size_t)BATCH * NNODE * NNODE * 2;   // 64 MiB
    const size_t SZ_M0Q  = (size_t)BATCH * NNODE * NNODE;       // 32 MiB
    const size_t SZ_PROJ = (size_t)ROWS_TOTAL * DM * 2;         // 8 MiB
    const size_t SZ_WT   = (size_t)DM * DIN * 2;
    const size_t SZ_UV   = (size_t)ROWS_TOTAL * 4;
    const size_t SZ_PS   = (size_t)BATCH * 128 * NNODE * 4;     // 8 MiB (max tier)

    const size_t NEED_I8  = SZ_M0B + SZ_M0Q + 2 * SZ_PROJ + SZ_WT + 3 * SZ_UV + SZ_PS;
    const bool use_i8 = ws_size >= NEED_I8;

    size_t off = 0;
    u16* M0b = (u16*)(ws + off); off += SZ_M0B;
    char* M0q = (char*)(ws + off); if (use_i8) off += SZ_M0Q;
    u16* dproj = (u16*)(ws + off); off += SZ_PROJ;
    u16* sproj = (u16*)(ws + off); off += SZ_PROJ;
    u16* Wt = (u16*)(ws + off); off += SZ_WT;
    float* u2 = (float*)(ws + off); off += SZ_UV;
    float* v2 = (float*)(ws + off); off += SZ_UV;
    float* ps = (float*)(ws + off); off += SZ_PS;
    float* spart = (float*)(ws + off);

    hipMemsetAsync(v2, 0, SZ_UV, stream);
    cvgm_prep_w<<<dim3(32, 8), 256, 0, stream>>>(W, Wt);
    cvgm_proj_mfma<<<dim3(256, 2), 512, 0, stream>>>(drone, sat, Wt, bias, dproj, sproj);

    if (use_i8) {
        cvgm_m0_mfma<1><<<dim3(16, 16, 8), 256, 0, stream>>>(dproj, sproj, M0b, M0q);
        for (int it = 0; it < 5; ++it) {
            cvgm_rc<1><<<dim3(64, 8), 256, 0, stream>>>(M0q, v2, u2, ps);
            cvgm_merge<<<ROWS_TOTAL / 256, 256, 0, stream>>>(ps, v2, 64);
        }
    } else {
        cvgm_m0_mfma<0><<<dim3(16, 16, 8), 256, 0, stream>>>(dproj, sproj, M0b, M0q);
        for (int it = 0; it < 5; ++it) {
            cvgm_rc<0><<<dim3(128, 8), 256, 0, stream>>>(M0b, v2, u2, ps);
            cvgm_merge<<<ROWS_TOTAL / 256, 256, 0, stream>>>(ps, v2, 128);
        }
    }

    cvgm_final<<<dim3(64, 8), 256, 0, stream>>>(M0b, u2, v2, out, spart);
    cvgm_score<<<BATCH, 256, 0, stream>>>(spart, score);
}

// Round 5
// 262.673 us; speedup vs baseline: 1.0865x; 1.0865x over previous
//
#include <hip/hip_runtime.h>
#include <math.h>

#define BATCH 8
#define NNODE 2048
#define DIN   1024
#define DM    256
#define ROWS_TOTAL (BATCH * NNODE)   // 16384

#define LOG2E 1.4426950408889634f
#define Q127  0.011359803471566641f   // LOG2E / 127
#define INV127 0.007874015748031496f  // 1/127

typedef unsigned short u16;
typedef __attribute__((ext_vector_type(8))) short short8;   // 8 bf16
typedef __attribute__((ext_vector_type(4))) float f32x4;

__device__ __forceinline__ u16 f2b(float f) {   // fp32 -> bf16 RNE
    union { float f; unsigned u; } v; v.f = f;
    unsigned r = v.u + 0x7fffu + ((v.u >> 16) & 1u);
    return (u16)(r >> 16);
}
// signed byte k (0..3) of dword -> float
__device__ __forceinline__ float dqi(unsigned wd, int k) {
    return (float)((int)(wd << ((3 - k) * 8)) >> 24);
}

// ---------------------------------------------------------------------------
// Kernel 0: Wt[c][k] = bf16(W[k][c])
// ---------------------------------------------------------------------------
__global__ __launch_bounds__(256) void cvgm_prep_w(
    const float* __restrict__ W, u16* __restrict__ Wt)
{
    __shared__ float t[32][33];
    const int tx = threadIdx.x & 31, ty = threadIdx.x >> 5;
    const int k0 = blockIdx.x * 32, c0 = blockIdx.y * 32;
    #pragma unroll
    for (int r = 0; r < 4; ++r) {
        const int kl = ty * 4 + r;
        t[kl][tx] = W[(size_t)(k0 + kl) * DM + c0 + tx];
    }
    __syncthreads();
    #pragma unroll
    for (int r = 0; r < 4; ++r) {
        const int cl = ty * 4 + r;
        Wt[(size_t)(c0 + cl) * DIN + k0 + tx] = f2b(t[tx][cl]);
    }
}

// ---------------------------------------------------------------------------
// Kernel 1: P = bf16(l2norm(X@W + b)).  64 rows x 256 cols per block,
// 512 threads = 8 waves (2 row-halves x 4 col-quarters), BK=64.
// grid (256, 2): y selects drone/sat.
// ---------------------------------------------------------------------------
__global__ __launch_bounds__(512) void cvgm_proj_mfma(
    const float* __restrict__ Xd, const float* __restrict__ Xs,
    const u16* __restrict__ Wt, const float* __restrict__ bias,
    u16* __restrict__ Pd, u16* __restrict__ Ps)
{
    __shared__ u16 As[64 * 64];     // 8 KB  chunk-swizzled [row][k]
    __shared__ u16 Bs[256 * 64];    // 32 KB chunk-swizzled [col][k]
    __shared__ float rsum[4][64];

    const float* X = blockIdx.y ? Xs : Xd;
    u16* P = blockIdx.y ? Ps : Pd;

    const int tid = threadIdx.x;
    const int lane = tid & 63, wid = tid >> 6;
    const int wr = wid >> 2, wc = wid & 3;
    const int l15 = lane & 15, l4 = lane >> 4;
    const int row0 = blockIdx.x * 64;

    f32x4 acc[2][4];
    #pragma unroll
    for (int m = 0; m < 2; ++m)
        #pragma unroll
        for (int n = 0; n < 4; ++n) acc[m][n] = (f32x4){0.f, 0.f, 0.f, 0.f};

    const int arow = tid >> 3, ac = tid & 7;   // A: 1 short8 chunk / thread

    for (int k0 = 0; k0 < DIN; k0 += 64) {
        const float* src = X + (size_t)(row0 + arow) * DIN + k0 + ac * 8;
        const float4 x0 = *(const float4*)src;
        const float4 x1 = *(const float4*)(src + 4);
        short8 wb[4];
        #pragma unroll
        for (int it = 0; it < 4; ++it) {
            const int id = it * 512 + tid;
            const int col = id >> 3, cc = id & 7;
            wb[it] = *(const short8*)(Wt + (size_t)col * DIN + k0 + cc * 8);
        }
        __syncthreads();
        short8 ap;
        ap[0]=(short)f2b(x0.x); ap[1]=(short)f2b(x0.y); ap[2]=(short)f2b(x0.z); ap[3]=(short)f2b(x0.w);
        ap[4]=(short)f2b(x1.x); ap[5]=(short)f2b(x1.y); ap[6]=(short)f2b(x1.z); ap[7]=(short)f2b(x1.w);
        *(short8*)(As + (arow * 8 + (ac ^ (arow & 7))) * 8) = ap;
        #pragma unroll
        for (int it = 0; it < 4; ++it) {
            const int id = it * 512 + tid;
            const int col = id >> 3, cc = id & 7;
            *(short8*)(Bs + (col * 8 + (cc ^ (col & 7))) * 8) = wb[it];
        }
        __syncthreads();
        #pragma unroll
        for (int ks = 0; ks < 2; ++ks) {
            const int ch = ks * 4 + l4;
            short8 af[2], bfr[4];
            #pragma unroll
            for (int m = 0; m < 2; ++m) {
                const int row = wr * 32 + m * 16 + l15;
                af[m] = *(const short8*)(As + (row * 8 + (ch ^ (row & 7))) * 8);
            }
            #pragma unroll
            for (int n = 0; n < 4; ++n) {
                const int col = wc * 64 + n * 16 + l15;
                bfr[n] = *(const short8*)(Bs + (col * 8 + (ch ^ (col & 7))) * 8);
            }
            #pragma unroll
            for (int m = 0; m < 2; ++m)
                #pragma unroll
                for (int n = 0; n < 4; ++n)
                    acc[m][n] = __builtin_amdgcn_mfma_f32_16x16x32_bf16(af[m], bfr[n], acc[m][n], 0, 0, 0);
        }
        __syncthreads();
    }

    #pragma unroll
    for (int n = 0; n < 4; ++n) {
        const float bv = bias[wc * 64 + n * 16 + l15];
        #pragma unroll
        for (int m = 0; m < 2; ++m)
            #pragma unroll
            for (int r = 0; r < 4; ++r) acc[m][n][r] += bv;
    }
    #pragma unroll
    for (int m = 0; m < 2; ++m)
        #pragma unroll
        for (int r = 0; r < 4; ++r) {
            float s = 0.f;
            #pragma unroll
            for (int n = 0; n < 4; ++n) s += acc[m][n][r] * acc[m][n][r];
            s += __shfl_xor(s, 1); s += __shfl_xor(s, 2);
            s += __shfl_xor(s, 4); s += __shfl_xor(s, 8);
            if (l15 == 0) rsum[wc][wr * 32 + m * 16 + l4 * 4 + r] = s;
        }
    __syncthreads();
    #pragma unroll
    for (int m = 0; m < 2; ++m)
        #pragma unroll
        for (int r = 0; r < 4; ++r) {
            const int row = wr * 32 + m * 16 + l4 * 4 + r;
            const float tot = rsum[0][row] + rsum[1][row] + rsum[2][row] + rsum[3][row];
            const float inv = 1.0f / fmaxf(sqrtf(tot), 1e-12f);
            #pragma unroll
            for (int n = 0; n < 4; ++n) {
                const int col = wc * 64 + n * 16 + l15;
                P[(size_t)(row0 + row) * DM + col] = f2b(acc[m][n][r] * inv);
            }
        }
}

// ---------------------------------------------------------------------------
// Kernel 2: M0q[b] = int8( 127 * D[b]@S[b]^T )  bf16 MFMA 128x128 tile.
// ---------------------------------------------------------------------------
__global__ __launch_bounds__(256) void cvgm_m0_mfma(
    const u16* __restrict__ Dp, const u16* __restrict__ Sp,
    char* __restrict__ Cq)
{
    __shared__ u16 As[128 * 64];
    __shared__ u16 Bs[128 * 64];

    const int tid = threadIdx.x;
    const int lane = tid & 63, wid = tid >> 6;
    const int wr = wid >> 1, wc = wid & 1;
    const int l15 = lane & 15, l4 = lane >> 4;
    const int bb = blockIdx.z;
    const int i0 = blockIdx.y * 128, j0 = blockIdx.x * 128;
    const u16* Db = Dp + (size_t)bb * NNODE * DM;
    const u16* Sb = Sp + (size_t)bb * NNODE * DM;

    f32x4 acc[4][4];
    #pragma unroll
    for (int m = 0; m < 4; ++m)
        #pragma unroll
        for (int n = 0; n < 4; ++n) acc[m][n] = (f32x4){0.f, 0.f, 0.f, 0.f};

    for (int k0 = 0; k0 < DM; k0 += 64) {
        short8 ra[4], rb[4];
        #pragma unroll
        for (int it = 0; it < 4; ++it) {
            const int id = it * 256 + tid;
            const int row = id >> 3, c = id & 7;
            ra[it] = *(const short8*)(Db + (size_t)(i0 + row) * DM + k0 + c * 8);
            rb[it] = *(const short8*)(Sb + (size_t)(j0 + row) * DM + k0 + c * 8);
        }
        __syncthreads();
        #pragma unroll
        for (int it = 0; it < 4; ++it) {
            const int id = it * 256 + tid;
            const int row = id >> 3, c = id & 7;
            const int sl = row * 8 + (c ^ (row & 7));
            *(short8*)(As + sl * 8) = ra[it];
            *(short8*)(Bs + sl * 8) = rb[it];
        }
        __syncthreads();
        #pragma unroll
        for (int ks = 0; ks < 2; ++ks) {
            const int ch = ks * 4 + l4;
            short8 af[4], bfr[4];
            #pragma unroll
            for (int m = 0; m < 4; ++m) {
                const int row = wr * 64 + m * 16 + l15;
                af[m] = *(const short8*)(As + (row * 8 + (ch ^ (row & 7))) * 8);
            }
            #pragma unroll
            for (int n = 0; n < 4; ++n) {
                const int col = wc * 64 + n * 16 + l15;
                bfr[n] = *(const short8*)(Bs + (col * 8 + (ch ^ (col & 7))) * 8);
            }
            #pragma unroll
            for (int m = 0; m < 4; ++m)
                #pragma unroll
                for (int n = 0; n < 4; ++n)
                    acc[m][n] = __builtin_amdgcn_mfma_f32_16x16x32_bf16(af[m], bfr[n], acc[m][n], 0, 0, 0);
        }
        __syncthreads();
    }

    char* Cqb = Cq + (size_t)bb * NNODE * NNODE;
    #pragma unroll
    for (int m = 0; m < 4; ++m) {
        const int row = i0 + wr * 64 + m * 16 + l4 * 4;
        #pragma unroll
        for (int n = 0; n < 4; ++n) {
            const int col = j0 + wc * 64 + n * 16 + l15;
            #pragma unroll
            for (int r = 0; r < 4; ++r) {
                int q = __float2int_rn(acc[m][n][r] * 127.f);
                q = q > 127 ? 127 : (q < -127 ? -127 : q);
                Cqb[(size_t)(row + r) * NNODE + col] = (char)q;
            }
        }
    }
}

// ---------------------------------------------------------------------------
// Kernel 3: fused Sinkhorn iteration, register-resident.
// Block = 4 waves; wave owns 4 rows; stripe = 16 rows; grid (128, 8).
// Thread owns 32 cols (2 segments of 16): FULL 2048-col coverage per wave.
// Factorized exponentials: p = exp2(q*Q127) once/elem; wv = exp2(-v2) per
// col (reused 4 rows); eu = exp2(-u2) per row.
// Phase A: u2[i] = log2 sum_j p*wv   Phase B: sc[j] += p*eu -> cps -> ps.
// ---------------------------------------------------------------------------
__global__ __launch_bounds__(256) void cvgm_rc(
    const char* __restrict__ Mq, const float* __restrict__ v2,
    float* __restrict__ u2, float* __restrict__ ps)
{
    __shared__ float cps[4][NNODE];   // 32 KB per-wave column partials

    const int tid = threadIdx.x;
    const int lane = tid & 63, w = tid >> 6;
    const int b = blockIdx.y, chunk = blockIdx.x;          // 128 chunks x 16 rows
    const size_t row0 = ((size_t)b << 11) + chunk * 16;
    const float* v2b = v2 + (b << 11);

    // wv[c] = exp2(-v2) at this thread's 32 cols (col = seg*1024 + lane*16 + k)
    float wv[32];
    #pragma unroll
    for (int s = 0; s < 2; ++s)
        #pragma unroll
        for (int k = 0; k < 4; ++k) {
            const float4 vv = *(const float4*)(v2b + s * 1024 + lane * 16 + k * 4);
            wv[s*16+k*4+0] = exp2f(-vv.x);
            wv[s*16+k*4+1] = exp2f(-vv.y);
            wv[s*16+k*4+2] = exp2f(-vv.z);
            wv[s*16+k*4+3] = exp2f(-vv.w);
        }

    const char* gb = Mq + row0 * NNODE + lane * 16;

    float sc[32];
    #pragma unroll
    for (int k = 0; k < 32; ++k) sc[k] = 0.f;

    #pragma unroll
    for (int rr = 0; rr < 4; ++rr) {
        const char* rsrc = gb + (size_t)(w * 4 + rr) * NNODE;
        const int4 d0 = *(const int4*)(rsrc);
        const int4 d1 = *(const int4*)(rsrc + 1024);
        const unsigned qd[8] = {(unsigned)d0.x, (unsigned)d0.y, (unsigned)d0.z, (unsigned)d0.w,
                                (unsigned)d1.x, (unsigned)d1.y, (unsigned)d1.z, (unsigned)d1.w};
        float p[32];
        #pragma unroll
        for (int q = 0; q < 8; ++q)
            #pragma unroll
            for (int k = 0; k < 4; ++k)
                p[q * 4 + k] = exp2f(dqi(qd[q], k) * Q127);
        float s = 0.f;
        #pragma unroll
        for (int k = 0; k < 32; ++k) s = fmaf(p[k], wv[k], s);
        #pragma unroll
        for (int off = 1; off < 64; off <<= 1) s += __shfl_xor(s, off);
        const float ur = __log2f(s);
        if (lane == 0) u2[row0 + w * 4 + rr] = ur;
        const float eu = exp2f(-ur);
        #pragma unroll
        for (int k = 0; k < 32; ++k) sc[k] = fmaf(p[k], eu, sc[k]);
    }

    #pragma unroll
    for (int s = 0; s < 2; ++s)
        #pragma unroll
        for (int k = 0; k < 4; ++k)
            *(float4*)(&cps[w][s * 1024 + lane * 16 + k * 4]) =
                make_float4(sc[s*16+k*4+0], sc[s*16+k*4+1], sc[s*16+k*4+2], sc[s*16+k*4+3]);
    __syncthreads();

    // block merge: thread sums 8 cols across 4 waves -> ps chunk
    const int j = tid * 8;
    float4 a0 = *(const float4*)(&cps[0][j]), a1 = *(const float4*)(&cps[0][j + 4]);
    #pragma unroll
    for (int ww = 1; ww < 4; ++ww) {
        const float4 b0 = *(const float4*)(&cps[ww][j]);
        const float4 b1 = *(const float4*)(&cps[ww][j + 4]);
        a0.x += b0.x; a0.y += b0.y; a0.z += b0.z; a0.w += b0.w;
        a1.x += b1.x; a1.y += b1.y; a1.z += b1.z; a1.w += b1.w;
    }
    float* dst = ps + ((size_t)(b * 128 + chunk)) * NNODE + j;
    *(float4*)dst = a0;
    *(float4*)(dst + 4) = a1;
}

// ---------------------------------------------------------------------------
// Kernel 4: v2[b,j] = log2( sum over 128 chunk partials )
// ---------------------------------------------------------------------------
__global__ __launch_bounds__(256) void cvgm_merge(
    const float* __restrict__ ps, float* __restrict__ v2)
{
    const int idx = blockIdx.x * 256 + threadIdx.x;
    const int b = idx >> 11, j = idx & 2047;
    float s = 0.f;
    #pragma unroll 8
    for (int c = 0; c < 128; ++c) s += ps[(size_t)(b * 128 + c) * NNODE + j];
    v2[idx] = __log2f(s);
}

// ---------------------------------------------------------------------------
// Kernel 5: assignment = exp2(q*Q127 - u2 - v2) -> out fp32; spart[row].
// One row per 128-thread block, grid (2048, 8).
// ---------------------------------------------------------------------------
__global__ __launch_bounds__(128) void cvgm_final(
    const char* __restrict__ Mq, const float* __restrict__ u2,
    const float* __restrict__ v2, float* __restrict__ out,
    float* __restrict__ spart)
{
    const int row = (blockIdx.y << 11) + blockIdx.x;
    const int t = threadIdx.x;              // 0..127, cols t*16..t*16+15
    const float ui = u2[row];
    const float* v2b = v2 + (blockIdx.y << 11);

    float vl[16];
    #pragma unroll
    for (int k = 0; k < 4; ++k)
        *(float4*)(vl + k * 4) = *(const float4*)(v2b + t * 16 + k * 4);

    const int4 d = *(const int4*)(Mq + (size_t)row * NNODE + t * 16);
    const unsigned qd[4] = {(unsigned)d.x, (unsigned)d.y, (unsigned)d.z, (unsigned)d.w};

    float a[16], acc = 0.f;
    #pragma unroll
    for (int q = 0; q < 4; ++q)
        #pragma unroll
        for (int k = 0; k < 4; ++k) {
            const float xq = dqi(qd[q], k);
            const float e = exp2f(fmaf(xq, Q127, -(ui + vl[q * 4 + k])));
            a[q * 4 + k] = e;
            acc = fmaf(e, xq, acc);
        }
    float* drow = out + (size_t)row * NNODE + t * 16;
    #pragma unroll
    for (int k = 0; k < 4; ++k)
        *(float4*)(drow + k * 4) = make_float4(a[k*4+0], a[k*4+1], a[k*4+2], a[k*4+3]);

    acc *= INV127;
    #pragma unroll
    for (int off = 1; off < 64; off <<= 1) acc += __shfl_xor(acc, off);
    __shared__ float sh[2];
    if ((t & 63) == 0) sh[t >> 6] = acc;
    __syncthreads();
    if (t == 0) spart[row] = sh[0] + sh[1];
}

// ---------------------------------------------------------------------------
// Kernel 6: match_score[b] = sum(spart[b,:]) / 2048
// ---------------------------------------------------------------------------
__global__ __launch_bounds__(256) void cvgm_score(
    const float* __restrict__ spart, float* __restrict__ score)
{
    const int b = blockIdx.x;
    float acc = 0.f;
    for (int t = threadIdx.x; t < NNODE; t += 256) acc += spart[(b << 11) + t];
    #pragma unroll
    for (int off = 1; off < 64; off <<= 1) acc += __shfl_xor(acc, off);
    __shared__ float sh[4];
    if ((threadIdx.x & 63) == 0) sh[threadIdx.x >> 6] = acc;
    __syncthreads();
    if (threadIdx.x == 0) score[b] = (sh[0] + sh[1] + sh[2] + sh[3]) * (1.0f / 2048.0f);
}

// ---------------------------------------------------------------------------
extern "C" void kernel_launch(void* const* d_in, const int* in_sizes, int n_in,
                              void* d_out, int out_size, void* d_ws, size_t ws_size,
                              hipStream_t stream) {
    (void)in_sizes; (void)n_in; (void)out_size; (void)ws_size;
    const float* drone = (const float*)d_in[0];
    const float* sat   = (const float*)d_in[1];
    const float* W     = (const float*)d_in[2];
    const float* bias  = (const float*)d_in[3];

    float* out   = (float*)d_out;
    float* score = out + (size_t)BATCH * NNODE * NNODE;

    char* ws = (char*)d_ws;
    const size_t SZ_M0Q  = (size_t)BATCH * NNODE * NNODE;       // 32 MiB
    const size_t SZ_PROJ = (size_t)ROWS_TOTAL * DM * 2;         // 8 MiB
    const size_t SZ_WT   = (size_t)DM * DIN * 2;                // 512 KiB
    const size_t SZ_UV   = (size_t)ROWS_TOTAL * 4;              // 64 KiB
    const size_t SZ_PS   = (size_t)BATCH * 128 * NNODE * 4;     // 8 MiB

    size_t off = 0;
    char* M0q  = ws + off;            off += SZ_M0Q;
    u16* dproj = (u16*)(ws + off);    off += SZ_PROJ;
    u16* sproj = (u16*)(ws + off);    off += SZ_PROJ;
    u16* Wt    = (u16*)(ws + off);    off += SZ_WT;
    float* u2  = (float*)(ws + off);  off += SZ_UV;
    float* v2  = (float*)(ws + off);  off += SZ_UV;
    float* ps  = (float*)(ws + off);  off += SZ_PS;
    float* spart = (float*)(ws + off);

    hipMemsetAsync(v2, 0, SZ_UV, stream);
    cvgm_prep_w<<<dim3(32, 8), 256, 0, stream>>>(W, Wt);
    cvgm_proj_mfma<<<dim3(256, 2), 512, 0, stream>>>(drone, sat, Wt, bias, dproj, sproj);
    cvgm_m0_mfma<<<dim3(16, 16, 8), 256, 0, stream>>>(dproj, sproj, M0q);

    for (int it = 0; it < 5; ++it) {
        cvgm_rc<<<dim3(128, 8), 256, 0, stream>>>(M0q, v2, u2, ps);
        cvgm_merge<<<ROWS_TOTAL / 256, 256, 0, stream>>>(ps, v2);
    }

    cvgm_final<<<dim3(2048, 8), 128, 0, stream>>>(M0q, u2, v2, out, spart);
    cvgm_score<<<BATCH, 256, 0, stream>>>(spart, score);
}